// Round 1
// baseline (158.953 us; speedup 1.0000x reference)
//
#include <hip/hip_runtime.h>
#include <hip/hip_bf16.h>

// UnivariateFlowMixture: N=1e6 points, C=8 channels, L=8 layers, B=32 bins.
// out = concat(z[N,C], log_j[N,C]) as float32.

#define TB 3.0f
#define NB 32      // bins
#define NC 8       // channels
#define NL 8       // layers
#define LN2 0.69314718055994530942f

__device__ __forceinline__ float softplusf(float v) {
    // jax.nn.softplus = logaddexp(v, 0)
    return fmaxf(v, 0.f) + log1pf(expf(-fabsf(v)));
}

// Per-(l,c) table layout in LDS: [0..32] cumw, [33..65] cumh, [66..98] derivs
#define TSTRIDE 99

__device__ __forceinline__ void spline_eval(const float* __restrict__ Tlc,
                                            float zc, float& zo, float& ldo) {
    const float* E  = Tlc;        // cumw edges [33]
    const float* Hc = Tlc + 33;   // cumh [33]
    const float* Dv = Tlc + 66;   // derivs [33]

    float xc = fminf(fmaxf(zc, -TB), TB);

    // branchless binary search: largest i in [0,31] with E[i] <= xc
    int i = (xc >= E[16]) ? 16 : 0;
    i += (xc >= E[i + 8]) ? 8 : 0;
    i += (xc >= E[i + 4]) ? 4 : 0;
    i += (xc >= E[i + 2]) ? 2 : 0;
    i += (xc >= E[i + 1]) ? 1 : 0;

    float xk  = E[i],  xk1 = E[i + 1];
    float yk  = Hc[i], yk1 = Hc[i + 1];
    float dk  = Dv[i], dk1 = Dv[i + 1];

    float wk    = xk1 - xk;
    float hk    = yk1 - yk;
    float invw  = __builtin_amdgcn_rcpf(wk);
    float delta = hk * invw;
    float th    = (xc - xk) * invw;
    float omt   = 1.f - th;
    float t1m   = th * omt;
    float th2   = th * th;

    float num = hk * fmaf(delta, th2, dk * t1m);
    float den = fmaf(fmaf(-2.f, delta, dk + dk1), t1m, delta);
    float y   = fmaf(num, __builtin_amdgcn_rcpf(den), yk);

    float dt    = delta * t1m;
    float inner = fmaf(dk1, th2, fmaf(dk, omt * omt, dt + dt));
    float dnum  = (delta * delta) * inner;
    // logdet = ln(dnum) - 2*ln(den) via fast log2
    float ld = LN2 * (__builtin_amdgcn_logf(dnum)
                      - 2.f * __builtin_amdgcn_logf(den));

    bool inside = (zc >= -TB) && (zc <= TB);
    zo  = inside ? y : zc;
    ldo = inside ? ld : 0.f;
}

extern "C" __global__ void __launch_bounds__(256)
flow_kernel(const float* __restrict__ x,
            const float* __restrict__ w,
            const float* __restrict__ h,
            const float* __restrict__ s,
            const float* __restrict__ bias,
            const float* __restrict__ lsc,
            float* __restrict__ out, int N)
{
    __shared__ float T[64 * TSTRIDE];   // 64 (l,c) tables
    __shared__ float Bb[NL + 1][NC];
    __shared__ float Sc[NL + 1][NC];
    __shared__ float LJC[NC];

    const int tid = threadIdx.x;

    // ---- build spline tables (one thread per (l,c)) ----
    if (tid < 64) {
        const int l = tid >> 3, c = tid & 7;
        float* cw = &T[tid * TSTRIDE];

        // widths -> cumw
        {
            const float* wr = w + (l * NC + c) * NB;
            float m = wr[0];
            for (int b = 1; b < NB; ++b) m = fmaxf(m, wr[b]);
            float sum = 0.f;
            for (int b = 0; b < NB; ++b) sum += expf(wr[b] - m);
            float inv = 1.f / sum;
            float acc = 0.f;
            cw[0] = -TB;
            for (int b = 0; b < NB; ++b) {
                float frac = 1e-3f + (1.f - 1e-3f * NB) * (expf(wr[b] - m) * inv);
                acc += frac;
                cw[b + 1] = 6.f * acc - 3.f;
            }
            cw[NB] = TB;
        }
        // heights -> cumh
        {
            float* ch = cw + 33;
            const float* hr = h + (l * NC + c) * NB;
            float m = hr[0];
            for (int b = 1; b < NB; ++b) m = fmaxf(m, hr[b]);
            float sum = 0.f;
            for (int b = 0; b < NB; ++b) sum += expf(hr[b] - m);
            float inv = 1.f / sum;
            float acc = 0.f;
            ch[0] = -TB;
            for (int b = 0; b < NB; ++b) {
                float frac = 1e-3f + (1.f - 1e-3f * NB) * (expf(hr[b] - m) * inv);
                acc += frac;
                ch[b + 1] = 6.f * acc - 3.f;
            }
            ch[NB] = TB;
        }
        // derivs
        {
            float* dv = cw + 66;
            const float* sr = s + (l * NC + c) * (NB - 1);
            const float cst = logf(expm1f(1.f - 1e-3f));
            const float dbound = 1e-3f + softplusf(cst);
            dv[0]  = dbound;
            dv[NB] = dbound;
            for (int k = 0; k < NB - 1; ++k)
                dv[k + 1] = 1e-3f + softplusf(sr[k]);
        }
    }
    // ---- affine params ----
    if (tid < (NL + 1) * NC) {
        const int l = tid >> 3, c = tid & 7;
        Bb[l][c] = bias[tid];
        Sc[l][c] = expf(-lsc[tid]);
    }
    if (tid < NC) {
        float a = 0.f;
        for (int l = 0; l <= NL; ++l) a += lsc[l * NC + tid];
        LJC[tid] = -a;
    }
    __syncthreads();

    const int n = blockIdx.x * 256 + tid;
    if (n >= N) return;

    const float xv = x[n];
    float z[NC], lj[NC];
#pragma unroll
    for (int c = 0; c < NC; ++c) { z[c] = xv; lj[c] = LJC[c]; }

#pragma unroll 1
    for (int l = 0; l < NL; ++l) {
        const float* Tl = &T[l * NC * TSTRIDE];
#pragma unroll
        for (int c = 0; c < NC; ++c) {
            float zc = (z[c] - Bb[l][c]) * Sc[l][c];
            float zo, ld;
            spline_eval(Tl + c * TSTRIDE, zc, zo, ld);
            z[c] = zo;
            lj[c] += ld;
        }
    }
#pragma unroll
    for (int c = 0; c < NC; ++c) z[c] = (z[c] - Bb[NL][c]) * Sc[NL][c];

    float4* oz = (float4*)(out + (size_t)n * NC);
    oz[0] = make_float4(z[0], z[1], z[2], z[3]);
    oz[1] = make_float4(z[4], z[5], z[6], z[7]);
    float4* ol = (float4*)(out + (size_t)N * NC + (size_t)n * NC);
    ol[0] = make_float4(lj[0], lj[1], lj[2], lj[3]);
    ol[1] = make_float4(lj[4], lj[5], lj[6], lj[7]);
}

extern "C" void kernel_launch(void* const* d_in, const int* in_sizes, int n_in,
                              void* d_out, int out_size, void* d_ws, size_t ws_size,
                              hipStream_t stream) {
    const float* x    = (const float*)d_in[0];
    const float* w    = (const float*)d_in[1];
    const float* h    = (const float*)d_in[2];
    const float* s    = (const float*)d_in[3];
    const float* bias = (const float*)d_in[4];
    const float* lsc  = (const float*)d_in[5];
    float* out = (float*)d_out;

    const int N = in_sizes[0];
    const int blocks = (N + 255) / 256;
    flow_kernel<<<blocks, 256, 0, stream>>>(x, w, h, s, bias, lsc, out, N);
}

// Round 2
// 108.301 us; speedup vs baseline: 1.4677x; 1.4677x over previous
//
#include <hip/hip_runtime.h>
#include <hip/hip_bf16.h>

// UnivariateFlowMixture: N=1e6 points, C=8 channels, L=8 layers, B=32 bins.
// Strategy: per-channel composed flow z(x), logj(x) is a fixed monotone C^1
// function -> tabulate on a dense grid (builder kernel), linearly interpolate
// in the main kernel, exact-fallback for steep/out-of-range cells.

#define TB 3.0f
#define NB 32
#define NC 8
#define NL 8
#define LN2 0.69314718055994530942f

#define GX0 -6.5f
#define GX1 6.5f
#define TZ 0.25f
#define TL 0.25f

#define PT_FLOATS (64 * 99)   // 64 (l,c) spline tables: 33 cumw | 33 cumh | 33 deriv

__device__ __forceinline__ float softplusf(float v) {
    return fmaxf(v, 0.f) + log1pf(expf(-fabsf(v)));
}

// Tlc: [0..32] cumw edges, [33..65] cumh, [66..98] derivs (LDS or global)
__device__ __forceinline__ void spline_eval(const float* __restrict__ Tlc,
                                            float zc, float& zo, float& ldo) {
    const float* E  = Tlc;
    const float* Hc = Tlc + 33;
    const float* Dv = Tlc + 66;

    float xc = fminf(fmaxf(zc, -TB), TB);

    int i = (xc >= E[16]) ? 16 : 0;
    i += (xc >= E[i + 8]) ? 8 : 0;
    i += (xc >= E[i + 4]) ? 4 : 0;
    i += (xc >= E[i + 2]) ? 2 : 0;
    i += (xc >= E[i + 1]) ? 1 : 0;

    float xk  = E[i],  xk1 = E[i + 1];
    float yk  = Hc[i], yk1 = Hc[i + 1];
    float dk  = Dv[i], dk1 = Dv[i + 1];

    float wk    = xk1 - xk;
    float hk    = yk1 - yk;
    float invw  = __builtin_amdgcn_rcpf(wk);
    float delta = hk * invw;
    float th    = (xc - xk) * invw;
    float omt   = 1.f - th;
    float t1m   = th * omt;
    float th2   = th * th;

    float num    = hk * fmaf(delta, th2, dk * t1m);
    float den    = fmaf(fmaf(-2.f, delta, dk + dk1), t1m, delta);
    float invden = __builtin_amdgcn_rcpf(den);
    float y      = fmaf(num, invden, yk);

    float dt    = delta * t1m;
    float inner = fmaf(dk1, th2, fmaf(dk, omt * omt, dt + dt));
    float dnum  = (delta * delta) * inner;
    // logdet = ln(dnum) - 2 ln(den) = ln(dnum * invden^2)  (one log)
    float r  = dnum * invden * invden;
    float ld = LN2 * __builtin_amdgcn_logf(r);

    bool inside = (zc >= -TB) && (zc <= TB);
    zo  = inside ? y : zc;
    ldo = inside ? ld : 0.f;
}

// ---------------- builder: composed table + global param copy ----------------
// tab layout: [G][C] float2{z, lj}   (row = 64 B)
// gparam: [PT_FLOATS] spline tables | [72] exp(-ls) | [8] -sum(ls)
extern "C" __global__ void __launch_bounds__(256)
build_kernel(const float* __restrict__ w, const float* __restrict__ h,
             const float* __restrict__ s, const float* __restrict__ bias,
             const float* __restrict__ lsc,
             float* __restrict__ tab, float* __restrict__ gparam,
             int G, float dx)
{
    __shared__ float T[PT_FLOATS];
    __shared__ float Sc[72], Bb[72], LJ[8];

    const int tid = threadIdx.x;

    if (tid < 64) {                       // widths -> cumw edges
        const int l = tid >> 3, c = tid & 7;
        float* cw = &T[tid * 99];
        const float* wr = w + (l * NC + c) * NB;
        float m = wr[0];
        for (int b = 1; b < NB; ++b) m = fmaxf(m, wr[b]);
        float sum = 0.f;
        for (int b = 0; b < NB; ++b) sum += expf(wr[b] - m);
        float inv = 1.f / sum;
        float acc = 0.f;
        cw[0] = -TB;
        for (int b = 0; b < NB; ++b) {
            acc += 1e-3f + (1.f - 1e-3f * NB) * (expf(wr[b] - m) * inv);
            cw[b + 1] = 6.f * acc - 3.f;
        }
        cw[NB] = TB;
    } else if (tid < 128) {               // heights -> cumh
        const int t = tid - 64;
        const int l = t >> 3, c = t & 7;
        float* ch = &T[t * 99 + 33];
        const float* hr = h + (l * NC + c) * NB;
        float m = hr[0];
        for (int b = 1; b < NB; ++b) m = fmaxf(m, hr[b]);
        float sum = 0.f;
        for (int b = 0; b < NB; ++b) sum += expf(hr[b] - m);
        float inv = 1.f / sum;
        float acc = 0.f;
        ch[0] = -TB;
        for (int b = 0; b < NB; ++b) {
            acc += 1e-3f + (1.f - 1e-3f * NB) * (expf(hr[b] - m) * inv);
            ch[b + 1] = 6.f * acc - 3.f;
        }
        ch[NB] = TB;
    } else if (tid < 192) {               // derivs
        const int t = tid - 128;
        const int l = t >> 3, c = t & 7;
        float* dv = &T[t * 99 + 66];
        const float* sr = s + (l * NC + c) * (NB - 1);
        const float cst = logf(expm1f(1.f - 1e-3f));
        const float dbound = 1e-3f + softplusf(cst);
        dv[0]  = dbound;
        dv[NB] = dbound;
        for (int k = 0; k < NB - 1; ++k)
            dv[k + 1] = 1e-3f + softplusf(sr[k]);
    }
    if (tid < 72) { Sc[tid] = expf(-lsc[tid]); Bb[tid] = bias[tid]; }
    if (tid < 8) {
        float a = 0.f;
        for (int l = 0; l <= NL; ++l) a += lsc[l * NC + tid];
        LJ[tid] = -a;
    }
    __syncthreads();

    if (blockIdx.x == 0) {                // param copy for exact fallback
        for (int k = tid; k < PT_FLOATS; k += 256) gparam[k] = T[k];
        if (tid < 72) gparam[PT_FLOATS + tid] = Sc[tid];
        if (tid < 8)  gparam[PT_FLOATS + 72 + tid] = LJ[tid];
    }

    const int e = blockIdx.x * 256 + tid;
    if (e < G * NC) {
        const int i = e >> 3, c = e & 7;
        float zc = fmaf((float)i, dx, GX0);
        float lj = LJ[c];
#pragma unroll 1
        for (int l = 0; l < NL; ++l) {
            zc = (zc - Bb[l * NC + c]) * Sc[l * NC + c];
            float ld;
            spline_eval(&T[(l * NC + c) * 99], zc, zc, ld);
            lj += ld;
        }
        zc = (zc - Bb[NL * NC + c]) * Sc[NL * NC + c];
        ((float2*)tab)[e] = make_float2(zc, lj);
    }
}

// ---------------- main: interpolate + rare exact fallback ----------------
extern "C" __global__ void __launch_bounds__(256)
interp_kernel(const float* __restrict__ x, const float* __restrict__ tab,
              const float* __restrict__ gparam, const float* __restrict__ bias,
              float* __restrict__ out, int N, int G, float dx, float invdx)
{
    const int n = blockIdx.x * 256 + threadIdx.x;
    if (n >= N) return;

    const float xv = x[n];
    int i = (int)floorf((xv - GX0) * invdx);
    const bool oor = !(xv > GX0 && xv < GX1);
    i = min(max(i, 0), G - 2);
    const float t = (xv - fmaf((float)i, dx, GX0)) * invdx;

    const float4* r0 = (const float4*)(tab + (size_t)i * (NC * 2));
    float4 a0 = r0[0], a1 = r0[1], a2 = r0[2], a3 = r0[3];
    float4 b0 = r0[4], b1 = r0[5], b2 = r0[6], b3 = r0[7];

    float z[NC], lj[NC];
    int flags = 0;
#define CH(cc, A, B, ZF, LF)                                            \
    { float dz = B.ZF - A.ZF, dl = B.LF - A.LF;                         \
      z[cc]  = fmaf(t, dz, A.ZF);                                       \
      lj[cc] = fmaf(t, dl, A.LF);                                       \
      if (fabsf(dz) > TZ || fabsf(dl) > TL) flags |= (1 << cc); }
    CH(0, a0, b0, x, y) CH(1, a0, b0, z, w)
    CH(2, a1, b1, x, y) CH(3, a1, b1, z, w)
    CH(4, a2, b2, x, y) CH(5, a2, b2, z, w)
    CH(6, a3, b3, x, y) CH(7, a3, b3, z, w)
#undef CH
    if (oor) flags = 0xff;

    if (flags) {                          // rare exact path
        const float* Scg = gparam + PT_FLOATS;
        const float* LJg = gparam + PT_FLOATS + 72;
#pragma unroll 1
        for (int c = 0; c < NC; ++c) {
            if (!((flags >> c) & 1)) continue;
            float zc = xv;
            float l_acc = LJg[c];
#pragma unroll 1
            for (int l = 0; l < NL; ++l) {
                zc = (zc - bias[l * NC + c]) * Scg[l * NC + c];
                float ld;
                spline_eval(gparam + (l * NC + c) * 99, zc, zc, ld);
                l_acc += ld;
            }
            z[c]  = (zc - bias[NL * NC + c]) * Scg[NL * NC + c];
            lj[c] = l_acc;
        }
    }

    float4* oz = (float4*)(out + (size_t)n * NC);
    oz[0] = make_float4(z[0], z[1], z[2], z[3]);
    oz[1] = make_float4(z[4], z[5], z[6], z[7]);
    float4* ol = (float4*)(out + (size_t)N * NC + (size_t)n * NC);
    ol[0] = make_float4(lj[0], lj[1], lj[2], lj[3]);
    ol[1] = make_float4(lj[4], lj[5], lj[6], lj[7]);
}

// ---------------- legacy monolithic kernel (ws-too-small fallback) ----------
#define TSTRIDE 99
extern "C" __global__ void __launch_bounds__(256)
flow_kernel(const float* __restrict__ x, const float* __restrict__ w,
            const float* __restrict__ h, const float* __restrict__ s,
            const float* __restrict__ bias, const float* __restrict__ lsc,
            float* __restrict__ out, int N)
{
    __shared__ float T[64 * TSTRIDE];
    __shared__ float Bb[NL + 1][NC];
    __shared__ float Sc[NL + 1][NC];
    __shared__ float LJC[NC];

    const int tid = threadIdx.x;
    if (tid < 64) {
        const int l = tid >> 3, c = tid & 7;
        float* cw = &T[tid * TSTRIDE];
        {
            const float* wr = w + (l * NC + c) * NB;
            float m = wr[0];
            for (int b = 1; b < NB; ++b) m = fmaxf(m, wr[b]);
            float sum = 0.f;
            for (int b = 0; b < NB; ++b) sum += expf(wr[b] - m);
            float inv = 1.f / sum;
            float acc = 0.f;
            cw[0] = -TB;
            for (int b = 0; b < NB; ++b) {
                acc += 1e-3f + (1.f - 1e-3f * NB) * (expf(wr[b] - m) * inv);
                cw[b + 1] = 6.f * acc - 3.f;
            }
            cw[NB] = TB;
        }
        {
            float* ch = cw + 33;
            const float* hr = h + (l * NC + c) * NB;
            float m = hr[0];
            for (int b = 1; b < NB; ++b) m = fmaxf(m, hr[b]);
            float sum = 0.f;
            for (int b = 0; b < NB; ++b) sum += expf(hr[b] - m);
            float inv = 1.f / sum;
            float acc = 0.f;
            ch[0] = -TB;
            for (int b = 0; b < NB; ++b) {
                acc += 1e-3f + (1.f - 1e-3f * NB) * (expf(hr[b] - m) * inv);
                ch[b + 1] = 6.f * acc - 3.f;
            }
            ch[NB] = TB;
        }
        {
            float* dv = cw + 66;
            const float* sr = s + (l * NC + c) * (NB - 1);
            const float cst = logf(expm1f(1.f - 1e-3f));
            const float dbound = 1e-3f + softplusf(cst);
            dv[0]  = dbound;
            dv[NB] = dbound;
            for (int k = 0; k < NB - 1; ++k)
                dv[k + 1] = 1e-3f + softplusf(sr[k]);
        }
    }
    if (tid < (NL + 1) * NC) {
        const int l = tid >> 3, c = tid & 7;
        Bb[l][c] = bias[tid];
        Sc[l][c] = expf(-lsc[tid]);
    }
    if (tid < NC) {
        float a = 0.f;
        for (int l = 0; l <= NL; ++l) a += lsc[l * NC + tid];
        LJC[tid] = -a;
    }
    __syncthreads();

    const int n = blockIdx.x * 256 + tid;
    if (n >= N) return;
    const float xv = x[n];
    float z[NC], lj[NC];
#pragma unroll
    for (int c = 0; c < NC; ++c) { z[c] = xv; lj[c] = LJC[c]; }
#pragma unroll 1
    for (int l = 0; l < NL; ++l) {
        const float* Tl = &T[l * NC * TSTRIDE];
#pragma unroll
        for (int c = 0; c < NC; ++c) {
            float zc = (z[c] - Bb[l][c]) * Sc[l][c];
            float zo, ld;
            spline_eval(Tl + c * TSTRIDE, zc, zo, ld);
            z[c] = zo;
            lj[c] += ld;
        }
    }
#pragma unroll
    for (int c = 0; c < NC; ++c) z[c] = (z[c] - Bb[NL][c]) * Sc[NL][c];

    float4* oz = (float4*)(out + (size_t)n * NC);
    oz[0] = make_float4(z[0], z[1], z[2], z[3]);
    oz[1] = make_float4(z[4], z[5], z[6], z[7]);
    float4* ol = (float4*)(out + (size_t)N * NC + (size_t)n * NC);
    ol[0] = make_float4(lj[0], lj[1], lj[2], lj[3]);
    ol[1] = make_float4(lj[4], lj[5], lj[6], lj[7]);
}

extern "C" void kernel_launch(void* const* d_in, const int* in_sizes, int n_in,
                              void* d_out, int out_size, void* d_ws, size_t ws_size,
                              hipStream_t stream) {
    const float* x    = (const float*)d_in[0];
    const float* w    = (const float*)d_in[1];
    const float* h    = (const float*)d_in[2];
    const float* s    = (const float*)d_in[3];
    const float* bias = (const float*)d_in[4];
    const float* lsc  = (const float*)d_in[5];
    float* out = (float*)d_out;
    const int N = in_sizes[0];

    int G = 16384;
    size_t need;
    for (;;) {
        need = ((size_t)G * NC * 2 + PT_FLOATS + 80) * sizeof(float);
        if (need <= ws_size || G <= 2048) break;
        G >>= 1;
    }

    if (need <= ws_size) {
        const float dx = (GX1 - GX0) / (float)(G - 1);
        float* tab    = (float*)d_ws;
        float* gparam = tab + (size_t)G * NC * 2;
        build_kernel<<<(G * NC + 255) / 256, 256, 0, stream>>>(
            w, h, s, bias, lsc, tab, gparam, G, dx);
        interp_kernel<<<(N + 255) / 256, 256, 0, stream>>>(
            x, tab, gparam, bias, out, N, G, dx, 1.f / dx);
    } else {
        flow_kernel<<<(N + 255) / 256, 256, 0, stream>>>(
            x, w, h, s, bias, lsc, out, N);
    }
}

// Round 3
// 91.309 us; speedup vs baseline: 1.7408x; 1.1861x over previous
//
#include <hip/hip_runtime.h>
#include <hip/hip_bf16.h>

// UnivariateFlowMixture: N=1e6 points, C=8 channels, L=8 layers, B=32 bins.
// Strategy: per-channel composed flow z(x), logj(x) is a fixed monotone C^1
// function -> tabulate on a dense grid (builder kernel), linearly interpolate
// in the main kernel, exact-fallback only for extreme/out-of-range cells.
// Round 3: G 16384->65536 (dx ~2e-4, hot region L2-resident) and flag
// thresholds 0.25->0.5 so the expensive divergent fallback is rare.

#define TB 3.0f
#define NB 32
#define NC 8
#define NL 8
#define LN2 0.69314718055994530942f

#define GX0 -6.5f
#define GX1 6.5f
#define TZ 0.5f
#define TL 0.5f

#define PT_FLOATS (64 * 99)   // 64 (l,c) spline tables: 33 cumw | 33 cumh | 33 deriv

__device__ __forceinline__ float softplusf(float v) {
    return fmaxf(v, 0.f) + log1pf(expf(-fabsf(v)));
}

// Tlc: [0..32] cumw edges, [33..65] cumh, [66..98] derivs (LDS or global)
__device__ __forceinline__ void spline_eval(const float* __restrict__ Tlc,
                                            float zc, float& zo, float& ldo) {
    const float* E  = Tlc;
    const float* Hc = Tlc + 33;
    const float* Dv = Tlc + 66;

    float xc = fminf(fmaxf(zc, -TB), TB);

    int i = (xc >= E[16]) ? 16 : 0;
    i += (xc >= E[i + 8]) ? 8 : 0;
    i += (xc >= E[i + 4]) ? 4 : 0;
    i += (xc >= E[i + 2]) ? 2 : 0;
    i += (xc >= E[i + 1]) ? 1 : 0;

    float xk  = E[i],  xk1 = E[i + 1];
    float yk  = Hc[i], yk1 = Hc[i + 1];
    float dk  = Dv[i], dk1 = Dv[i + 1];

    float wk    = xk1 - xk;
    float hk    = yk1 - yk;
    float invw  = __builtin_amdgcn_rcpf(wk);
    float delta = hk * invw;
    float th    = (xc - xk) * invw;
    float omt   = 1.f - th;
    float t1m   = th * omt;
    float th2   = th * th;

    float num    = hk * fmaf(delta, th2, dk * t1m);
    float den    = fmaf(fmaf(-2.f, delta, dk + dk1), t1m, delta);
    float invden = __builtin_amdgcn_rcpf(den);
    float y      = fmaf(num, invden, yk);

    float dt    = delta * t1m;
    float inner = fmaf(dk1, th2, fmaf(dk, omt * omt, dt + dt));
    float dnum  = (delta * delta) * inner;
    float r  = dnum * invden * invden;
    float ld = LN2 * __builtin_amdgcn_logf(r);

    bool inside = (zc >= -TB) && (zc <= TB);
    zo  = inside ? y : zc;
    ldo = inside ? ld : 0.f;
}

// ---------------- builder: composed table + global param copy ----------------
// tab layout: [G][C] float2{z, lj}   (row = 64 B)
// gparam: [PT_FLOATS] spline tables | [72] exp(-ls) | [8] -sum(ls)
extern "C" __global__ void __launch_bounds__(256)
build_kernel(const float* __restrict__ w, const float* __restrict__ h,
             const float* __restrict__ s, const float* __restrict__ bias,
             const float* __restrict__ lsc,
             float* __restrict__ tab, float* __restrict__ gparam,
             int G, float dx)
{
    __shared__ float T[PT_FLOATS];
    __shared__ float Sc[72], Bb[72], LJ[8];

    const int tid = threadIdx.x;

    if (tid < 64) {                       // widths -> cumw edges
        const int l = tid >> 3, c = tid & 7;
        float* cw = &T[tid * 99];
        const float* wr = w + (l * NC + c) * NB;
        float m = wr[0];
        for (int b = 1; b < NB; ++b) m = fmaxf(m, wr[b]);
        float sum = 0.f;
        for (int b = 0; b < NB; ++b) sum += expf(wr[b] - m);
        float inv = 1.f / sum;
        float acc = 0.f;
        cw[0] = -TB;
        for (int b = 0; b < NB; ++b) {
            acc += 1e-3f + (1.f - 1e-3f * NB) * (expf(wr[b] - m) * inv);
            cw[b + 1] = 6.f * acc - 3.f;
        }
        cw[NB] = TB;
    } else if (tid < 128) {               // heights -> cumh
        const int t = tid - 64;
        const int l = t >> 3, c = t & 7;
        float* ch = &T[t * 99 + 33];
        const float* hr = h + (l * NC + c) * NB;
        float m = hr[0];
        for (int b = 1; b < NB; ++b) m = fmaxf(m, hr[b]);
        float sum = 0.f;
        for (int b = 0; b < NB; ++b) sum += expf(hr[b] - m);
        float inv = 1.f / sum;
        float acc = 0.f;
        ch[0] = -TB;
        for (int b = 0; b < NB; ++b) {
            acc += 1e-3f + (1.f - 1e-3f * NB) * (expf(hr[b] - m) * inv);
            ch[b + 1] = 6.f * acc - 3.f;
        }
        ch[NB] = TB;
    } else if (tid < 192) {               // derivs
        const int t = tid - 128;
        const int l = t >> 3, c = t & 7;
        float* dv = &T[t * 99 + 66];
        const float* sr = s + (l * NC + c) * (NB - 1);
        const float cst = logf(expm1f(1.f - 1e-3f));
        const float dbound = 1e-3f + softplusf(cst);
        dv[0]  = dbound;
        dv[NB] = dbound;
        for (int k = 0; k < NB - 1; ++k)
            dv[k + 1] = 1e-3f + softplusf(sr[k]);
    }
    if (tid < 72) { Sc[tid] = expf(-lsc[tid]); Bb[tid] = bias[tid]; }
    if (tid < 8) {
        float a = 0.f;
        for (int l = 0; l <= NL; ++l) a += lsc[l * NC + tid];
        LJ[tid] = -a;
    }
    __syncthreads();

    if (blockIdx.x == 0) {                // param copy for exact fallback
        for (int k = tid; k < PT_FLOATS; k += 256) gparam[k] = T[k];
        if (tid < 72) gparam[PT_FLOATS + tid] = Sc[tid];
        if (tid < 8)  gparam[PT_FLOATS + 72 + tid] = LJ[tid];
    }

    const int e = blockIdx.x * 256 + tid;
    if (e < G * NC) {
        const int i = e >> 3, c = e & 7;
        float zc = fmaf((float)i, dx, GX0);
        float lj = LJ[c];
#pragma unroll 1
        for (int l = 0; l < NL; ++l) {
            zc = (zc - Bb[l * NC + c]) * Sc[l * NC + c];
            float ld;
            spline_eval(&T[(l * NC + c) * 99], zc, zc, ld);
            lj += ld;
        }
        zc = (zc - Bb[NL * NC + c]) * Sc[NL * NC + c];
        ((float2*)tab)[e] = make_float2(zc, lj);
    }
}

// ---------------- main: interpolate + rare exact fallback ----------------
extern "C" __global__ void __launch_bounds__(256)
interp_kernel(const float* __restrict__ x, const float* __restrict__ tab,
              const float* __restrict__ gparam, const float* __restrict__ bias,
              float* __restrict__ out, int N, int G, float dx, float invdx)
{
    const int n = blockIdx.x * 256 + threadIdx.x;
    if (n >= N) return;

    const float xv = x[n];
    int i = (int)floorf((xv - GX0) * invdx);
    const bool oor = !(xv > GX0 && xv < GX1);
    i = min(max(i, 0), G - 2);
    const float t = (xv - fmaf((float)i, dx, GX0)) * invdx;

    const float4* r0 = (const float4*)(tab + (size_t)i * (NC * 2));
    float4 a0 = r0[0], a1 = r0[1], a2 = r0[2], a3 = r0[3];
    float4 b0 = r0[4], b1 = r0[5], b2 = r0[6], b3 = r0[7];

    float z[NC], lj[NC];
    int flags = 0;
#define CH(cc, A, B, ZF, LF)                                            \
    { float dz = B.ZF - A.ZF, dl = B.LF - A.LF;                         \
      z[cc]  = fmaf(t, dz, A.ZF);                                       \
      lj[cc] = fmaf(t, dl, A.LF);                                       \
      if (fabsf(dz) > TZ || fabsf(dl) > TL) flags |= (1 << cc); }
    CH(0, a0, b0, x, y) CH(1, a0, b0, z, w)
    CH(2, a1, b1, x, y) CH(3, a1, b1, z, w)
    CH(4, a2, b2, x, y) CH(5, a2, b2, z, w)
    CH(6, a3, b3, x, y) CH(7, a3, b3, z, w)
#undef CH
    if (oor) flags = 0xff;

    if (flags) {                          // rare exact path
        const float* Scg = gparam + PT_FLOATS;
        const float* LJg = gparam + PT_FLOATS + 72;
#pragma unroll 1
        for (int c = 0; c < NC; ++c) {
            if (!((flags >> c) & 1)) continue;
            float zc = xv;
            float l_acc = LJg[c];
#pragma unroll 1
            for (int l = 0; l < NL; ++l) {
                zc = (zc - bias[l * NC + c]) * Scg[l * NC + c];
                float ld;
                spline_eval(gparam + (l * NC + c) * 99, zc, zc, ld);
                l_acc += ld;
            }
            z[c]  = (zc - bias[NL * NC + c]) * Scg[NL * NC + c];
            lj[c] = l_acc;
        }
    }

    float4* oz = (float4*)(out + (size_t)n * NC);
    oz[0] = make_float4(z[0], z[1], z[2], z[3]);
    oz[1] = make_float4(z[4], z[5], z[6], z[7]);
    float4* ol = (float4*)(out + (size_t)N * NC + (size_t)n * NC);
    ol[0] = make_float4(lj[0], lj[1], lj[2], lj[3]);
    ol[1] = make_float4(lj[4], lj[5], lj[6], lj[7]);
}

// ---------------- legacy monolithic kernel (ws-too-small fallback) ----------
#define TSTRIDE 99
extern "C" __global__ void __launch_bounds__(256)
flow_kernel(const float* __restrict__ x, const float* __restrict__ w,
            const float* __restrict__ h, const float* __restrict__ s,
            const float* __restrict__ bias, const float* __restrict__ lsc,
            float* __restrict__ out, int N)
{
    __shared__ float T[64 * TSTRIDE];
    __shared__ float Bb[NL + 1][NC];
    __shared__ float Sc[NL + 1][NC];
    __shared__ float LJC[NC];

    const int tid = threadIdx.x;
    if (tid < 64) {
        const int l = tid >> 3, c = tid & 7;
        float* cw = &T[tid * TSTRIDE];
        {
            const float* wr = w + (l * NC + c) * NB;
            float m = wr[0];
            for (int b = 1; b < NB; ++b) m = fmaxf(m, wr[b]);
            float sum = 0.f;
            for (int b = 0; b < NB; ++b) sum += expf(wr[b] - m);
            float inv = 1.f / sum;
            float acc = 0.f;
            cw[0] = -TB;
            for (int b = 0; b < NB; ++b) {
                acc += 1e-3f + (1.f - 1e-3f * NB) * (expf(wr[b] - m) * inv);
                cw[b + 1] = 6.f * acc - 3.f;
            }
            cw[NB] = TB;
        }
        {
            float* ch = cw + 33;
            const float* hr = h + (l * NC + c) * NB;
            float m = hr[0];
            for (int b = 1; b < NB; ++b) m = fmaxf(m, hr[b]);
            float sum = 0.f;
            for (int b = 0; b < NB; ++b) sum += expf(hr[b] - m);
            float inv = 1.f / sum;
            float acc = 0.f;
            ch[0] = -TB;
            for (int b = 0; b < NB; ++b) {
                acc += 1e-3f + (1.f - 1e-3f * NB) * (expf(hr[b] - m) * inv);
                ch[b + 1] = 6.f * acc - 3.f;
            }
            ch[NB] = TB;
        }
        {
            float* dv = cw + 66;
            const float* sr = s + (l * NC + c) * (NB - 1);
            const float cst = logf(expm1f(1.f - 1e-3f));
            const float dbound = 1e-3f + softplusf(cst);
            dv[0]  = dbound;
            dv[NB] = dbound;
            for (int k = 0; k < NB - 1; ++k)
                dv[k + 1] = 1e-3f + softplusf(sr[k]);
        }
    }
    if (tid < (NL + 1) * NC) {
        const int l = tid >> 3, c = tid & 7;
        Bb[l][c] = bias[tid];
        Sc[l][c] = expf(-lsc[tid]);
    }
    if (tid < NC) {
        float a = 0.f;
        for (int l = 0; l <= NL; ++l) a += lsc[l * NC + tid];
        LJC[tid] = -a;
    }
    __syncthreads();

    const int n = blockIdx.x * 256 + tid;
    if (n >= N) return;
    const float xv = x[n];
    float z[NC], lj[NC];
#pragma unroll
    for (int c = 0; c < NC; ++c) { z[c] = xv; lj[c] = LJC[c]; }
#pragma unroll 1
    for (int l = 0; l < NL; ++l) {
        const float* Tl = &T[l * NC * TSTRIDE];
#pragma unroll
        for (int c = 0; c < NC; ++c) {
            float zc = (z[c] - Bb[l][c]) * Sc[l][c];
            float zo, ld;
            spline_eval(Tl + c * TSTRIDE, zc, zo, ld);
            z[c] = zo;
            lj[c] += ld;
        }
    }
#pragma unroll
    for (int c = 0; c < NC; ++c) z[c] = (z[c] - Bb[NL][c]) * Sc[NL][c];

    float4* oz = (float4*)(out + (size_t)n * NC);
    oz[0] = make_float4(z[0], z[1], z[2], z[3]);
    oz[1] = make_float4(z[4], z[5], z[6], z[7]);
    float4* ol = (float4*)(out + (size_t)N * NC + (size_t)n * NC);
    ol[0] = make_float4(lj[0], lj[1], lj[2], lj[3]);
    ol[1] = make_float4(lj[4], lj[5], lj[6], lj[7]);
}

extern "C" void kernel_launch(void* const* d_in, const int* in_sizes, int n_in,
                              void* d_out, int out_size, void* d_ws, size_t ws_size,
                              hipStream_t stream) {
    const float* x    = (const float*)d_in[0];
    const float* w    = (const float*)d_in[1];
    const float* h    = (const float*)d_in[2];
    const float* s    = (const float*)d_in[3];
    const float* bias = (const float*)d_in[4];
    const float* lsc  = (const float*)d_in[5];
    float* out = (float*)d_out;
    const int N = in_sizes[0];

    int G = 65536;
    size_t need;
    for (;;) {
        need = ((size_t)G * NC * 2 + PT_FLOATS + 80) * sizeof(float);
        if (need <= ws_size || G <= 2048) break;
        G >>= 1;
    }

    if (need <= ws_size) {
        const float dx = (GX1 - GX0) / (float)(G - 1);
        float* tab    = (float*)d_ws;
        float* gparam = tab + (size_t)G * NC * 2;
        build_kernel<<<(G * NC + 255) / 256, 256, 0, stream>>>(
            w, h, s, bias, lsc, tab, gparam, G, dx);
        interp_kernel<<<(N + 255) / 256, 256, 0, stream>>>(
            x, tab, gparam, bias, out, N, G, dx, 1.f / dx);
    } else {
        flow_kernel<<<(N + 255) / 256, 256, 0, stream>>>(
            x, w, h, s, bias, lsc, out, N);
    }
}